// Round 1
// baseline (88.378 us; speedup 1.0000x reference)
//
#include <hip/hip_runtime.h>
#include <math.h>

// ---------------------------------------------------------------------------
// PrefrontalCortex: memory-augmented LSTM cell, batch=1, fp32.
// All matmuls are GEMVs -> memory-bound. 11 kernels in dependency order.
// ---------------------------------------------------------------------------

#define INPUT_DIM 2048
#define HIDDEN_DIM 2048
#define MEM_SLOTS 4096
#define MEM_DIM 1024
#define OUTPUT_DIM 2048

static __device__ __forceinline__ float sigmoidf_(float x) {
    return 1.0f / (1.0f + expf(-x));
}

// Generic wave-per-row GEMV: out[r] = act(dot(W[r,:], v) + bias[r])
// k4 = K/4 (row length in float4). act: 0 = none, 1 = tanh.
__global__ void gemv64_kernel(const float* __restrict__ W, const float* __restrict__ v,
                              const float* __restrict__ bias, float* __restrict__ out,
                              int rows, int k4, int act) {
    int wave = (int)((blockIdx.x * blockDim.x + threadIdx.x) >> 6);
    int lane = threadIdx.x & 63;
    if (wave >= rows) return;
    const float4* Wr = (const float4*)W + (size_t)wave * (size_t)k4;
    const float4* v4 = (const float4*)v;
    float acc = 0.f;
    for (int i = lane; i < k4; i += 64) {
        float4 w4 = Wr[i];
        float4 x4 = v4[i];
        acc = fmaf(w4.x, x4.x, acc);
        acc = fmaf(w4.y, x4.y, acc);
        acc = fmaf(w4.z, x4.z, acc);
        acc = fmaf(w4.w, x4.w, acc);
    }
#pragma unroll
    for (int off = 32; off > 0; off >>= 1) acc += __shfl_down(acc, off);
    if (lane == 0) {
        float r = acc + (bias ? bias[wave] : 0.f);
        if (act == 1) r = tanhf(r);
        out[wave] = r;
    }
}

// gates[r] = dot(W_ih[r,:3072], xcat) + b_ih[r] + dot(W_hh[r,:2048], h) + b_hh[r]
__global__ void gates_kernel(const float* __restrict__ W_ih, const float* __restrict__ W_hh,
                             const float* __restrict__ b_ih, const float* __restrict__ b_hh,
                             const float* __restrict__ xcat, const float* __restrict__ h,
                             float* __restrict__ gates) {
    int wave = (int)((blockIdx.x * blockDim.x + threadIdx.x) >> 6);
    int lane = threadIdx.x & 63;
    if (wave >= 4 * HIDDEN_DIM) return;
    const float4* Wi = (const float4*)W_ih + (size_t)wave * 768;  // 3072/4
    const float4* Wh = (const float4*)W_hh + (size_t)wave * 512;  // 2048/4
    const float4* xc4 = (const float4*)xcat;
    const float4* h4 = (const float4*)h;
    float acc = 0.f;
#pragma unroll
    for (int j = 0; j < 12; ++j) {
        int i = lane + j * 64;
        float4 w4 = Wi[i];
        float4 x4 = xc4[i];
        acc = fmaf(w4.x, x4.x, acc);
        acc = fmaf(w4.y, x4.y, acc);
        acc = fmaf(w4.z, x4.z, acc);
        acc = fmaf(w4.w, x4.w, acc);
    }
#pragma unroll
    for (int j = 0; j < 8; ++j) {
        int i = lane + j * 64;
        float4 w4 = Wh[i];
        float4 x4 = h4[i];
        acc = fmaf(w4.x, x4.x, acc);
        acc = fmaf(w4.y, x4.y, acc);
        acc = fmaf(w4.z, x4.z, acc);
        acc = fmaf(w4.w, x4.w, acc);
    }
#pragma unroll
    for (int off = 32; off > 0; off >>= 1) acc += __shfl_down(acc, off);
    if (lane == 0) gates[wave] = acc + b_ih[wave] + b_hh[wave];
}

// softmax over sim[0:4096] -> rw; usage_out = usage + rw.  One block, 1024 thr.
__global__ void softmax_rw_kernel(const float* __restrict__ sim, const float* __restrict__ usage,
                                  float* __restrict__ rw, float* __restrict__ usage_out) {
    __shared__ float sm[16];
    int tid = threadIdx.x;
    int lane = tid & 63, wid = tid >> 6;
    float v0 = sim[tid], v1 = sim[tid + 1024], v2 = sim[tid + 2048], v3 = sim[tid + 3072];
    float m = fmaxf(fmaxf(v0, v1), fmaxf(v2, v3));
#pragma unroll
    for (int off = 32; off > 0; off >>= 1) m = fmaxf(m, __shfl_down(m, off));
    if (lane == 0) sm[wid] = m;
    __syncthreads();
    if (tid == 0) {
        float mm = sm[0];
        for (int i = 1; i < 16; ++i) mm = fmaxf(mm, sm[i]);
        sm[0] = mm;
    }
    __syncthreads();
    float mm = sm[0];
    float e0 = expf(v0 - mm), e1 = expf(v1 - mm), e2 = expf(v2 - mm), e3 = expf(v3 - mm);
    float s = e0 + e1 + e2 + e3;
#pragma unroll
    for (int off = 32; off > 0; off >>= 1) s += __shfl_down(s, off);
    __syncthreads();
    if (lane == 0) sm[wid] = s;
    __syncthreads();
    if (tid == 0) {
        float ss = 0.f;
        for (int i = 0; i < 16; ++i) ss += sm[i];
        sm[0] = ss;
    }
    __syncthreads();
    float inv = 1.f / sm[0];
    float r0 = e0 * inv, r1 = e1 * inv, r2 = e2 * inv, r3 = e3 * inv;
    rw[tid] = r0; rw[tid + 1024] = r1; rw[tid + 2048] = r2; rw[tid + 3072] = r3;
    usage_out[tid]        = usage[tid]        + r0;
    usage_out[tid + 1024] = usage[tid + 1024] + r1;
    usage_out[tid + 2048] = usage[tid + 2048] + r2;
    usage_out[tid + 3072] = usage[tid + 3072] + r3;
}

// Stage 1 of read_vec = rw @ memory: 64 blocks, each reduces 64 rows over all
// 1024 cols (256 thr x float4). partial[chunk][1024].
__global__ void readvec_partial_kernel(const float* __restrict__ memory,
                                       const float* __restrict__ rw,
                                       float* __restrict__ partial) {
    int t = threadIdx.x;   // 256
    int chunk = blockIdx.x; // 64
    const float4* mem4 = (const float4*)memory;
    float4 acc = make_float4(0.f, 0.f, 0.f, 0.f);
    int s0 = chunk * 64;
    for (int s = s0; s < s0 + 64; ++s) {
        float w = rw[s];
        float4 m = mem4[(size_t)s * 256 + t];
        acc.x = fmaf(w, m.x, acc.x);
        acc.y = fmaf(w, m.y, acc.y);
        acc.z = fmaf(w, m.z, acc.z);
        acc.w = fmaf(w, m.w, acc.w);
    }
    ((float4*)partial)[chunk * 256 + t] = acc;
}

// Stage 2: read_vec[c] = sum over 64 chunks; also build concat buffers.
// xcat = [x (2048) | read_vec (1024)], hvcat[2048:] = read_vec.
__global__ void readvec_reduce_kernel(const float* __restrict__ partial,
                                      const float* __restrict__ x,
                                      float* __restrict__ xcat, float* __restrict__ hvcat) {
    int c = threadIdx.x;  // 1024
    float s = 0.f;
    for (int k = 0; k < 64; ++k) s += partial[k * 1024 + c];
    xcat[2048 + c] = s;
    hvcat[2048 + c] = s;
    xcat[c] = x[c];
    xcat[1024 + c] = x[1024 + c];
}

// LSTM elementwise: 2048 elems.
__global__ void lstm_elem_kernel(const float* __restrict__ gates, const float* __restrict__ c_prev,
                                 float* __restrict__ c_out, float* __restrict__ h_out,
                                 float* __restrict__ hvcat) {
    int t = blockIdx.x * blockDim.x + threadIdx.x;
    if (t >= HIDDEN_DIM) return;
    float ig = sigmoidf_(gates[t]);
    float fg = sigmoidf_(gates[2048 + t]);
    float gg = tanhf(gates[4096 + t]);
    float og = sigmoidf_(gates[6144 + t]);
    float c = fg * c_prev[t] + ig * gg;
    float h = og * tanhf(c);
    c_out[t] = c;
    h_out[t] = h;
    hvcat[t] = h;
}

// softmax over params[3072:7168] scaled by sigmoid(params[7168]) -> wv;
// also precompute erase = sigmoid(params[1024:2048]), add = tanh(params[2048:3072]).
__global__ void softmax_w_kernel(const float* __restrict__ params, float* __restrict__ wv,
                                 float* __restrict__ erase, float* __restrict__ addv) {
    __shared__ float sm[16];
    int tid = threadIdx.x;
    int lane = tid & 63, wid = tid >> 6;
    const float* logits = params + 3072;
    float v0 = logits[tid], v1 = logits[tid + 1024], v2 = logits[tid + 2048], v3 = logits[tid + 3072];
    float m = fmaxf(fmaxf(v0, v1), fmaxf(v2, v3));
#pragma unroll
    for (int off = 32; off > 0; off >>= 1) m = fmaxf(m, __shfl_down(m, off));
    if (lane == 0) sm[wid] = m;
    __syncthreads();
    if (tid == 0) {
        float mm = sm[0];
        for (int i = 1; i < 16; ++i) mm = fmaxf(mm, sm[i]);
        sm[0] = mm;
    }
    __syncthreads();
    float mm = sm[0];
    float e0 = expf(v0 - mm), e1 = expf(v1 - mm), e2 = expf(v2 - mm), e3 = expf(v3 - mm);
    float s = e0 + e1 + e2 + e3;
#pragma unroll
    for (int off = 32; off > 0; off >>= 1) s += __shfl_down(s, off);
    __syncthreads();
    if (lane == 0) sm[wid] = s;
    __syncthreads();
    if (tid == 0) {
        float ss = 0.f;
        for (int i = 0; i < 16; ++i) ss += sm[i];
        sm[0] = ss;
    }
    __syncthreads();
    float gate = sigmoidf_(params[7168]);
    float scale = gate / sm[0];
    wv[tid] = e0 * scale; wv[tid + 1024] = e1 * scale;
    wv[tid + 2048] = e2 * scale; wv[tid + 3072] = e3 * scale;
    erase[tid] = sigmoidf_(params[1024 + tid]);
    addv[tid]  = tanhf(params[2048 + tid]);
}

// new_memory[s,:] = mask(usage_new[s]) * memory[s,:] * (1 - w[s]*erase) + w[s]*add
__global__ void memupdate_kernel(const float* __restrict__ memory, const float* __restrict__ wv,
                                 const float* __restrict__ erase, const float* __restrict__ addv,
                                 const float* __restrict__ usage_new, float* __restrict__ newmem) {
    int s = blockIdx.x;   // 4096
    int t = threadIdx.x;  // 256 (float4 over 1024 cols)
    float w = wv[s];
    float mask = (usage_new[s] < 0.1f) ? 0.f : 1.f;
    float4 m = ((const float4*)memory)[(size_t)s * 256 + t];
    float4 e = ((const float4*)erase)[t];
    float4 a = ((const float4*)addv)[t];
    float4 r;
    r.x = mask * m.x * (1.f - w * e.x) + w * a.x;
    r.y = mask * m.y * (1.f - w * e.y) + w * a.y;
    r.z = mask * m.z * (1.f - w * e.z) + w * a.z;
    r.w = mask * m.w * (1.f - w * e.w) + w * a.w;
    ((float4*)newmem)[(size_t)s * 256 + t] = r;
}

extern "C" void kernel_launch(void* const* d_in, const int* in_sizes, int n_in,
                              void* d_out_, int out_size, void* d_ws, size_t ws_size,
                              hipStream_t stream) {
    const float* x      = (const float*)d_in[0];
    const float* h_prev = (const float*)d_in[1];
    const float* c_prev = (const float*)d_in[2];
    const float* memory = (const float*)d_in[3];
    const float* usage  = (const float*)d_in[4];
    const float* read_W = (const float*)d_in[5];
    const float* read_b = (const float*)d_in[6];
    const float* W_ih   = (const float*)d_in[7];
    const float* b_ih   = (const float*)d_in[8];
    const float* W_hh   = (const float*)d_in[9];
    const float* b_hh   = (const float*)d_in[10];
    const float* head_W = (const float*)d_in[11];
    const float* head_b = (const float*)d_in[12];
    const float* out_W  = (const float*)d_in[13];
    const float* out_b  = (const float*)d_in[14];

    float* d_out = (float*)d_out_;
    float* ws = (float*)d_ws;

    // workspace layout (floats)
    float* xcat    = ws + 0;      // 3072: [x | read_vec]
    float* hvcat   = ws + 3072;   // 3072: [h_new | read_vec]
    float* rk      = ws + 6144;   // 1024
    float* sim     = ws + 7168;   // 4096
    float* rw      = ws + 11264;  // 4096
    float* gates   = ws + 15360;  // 8192
    float* params  = ws + 23552;  // 7169 (padded)
    float* wv      = ws + 30976;  // 4096
    float* erase   = ws + 35072;  // 1024
    float* addv    = ws + 36096;  // 1024
    float* partial = ws + 37120;  // 64*1024

    // output layout (floats): out | h_new | c_new | new_memory | usage_new
    float* out       = d_out;
    float* h_new     = d_out + 2048;
    float* c_new     = d_out + 4096;
    float* newmem    = d_out + 6144;
    float* usage_new = d_out + 6144 + (size_t)MEM_SLOTS * MEM_DIM;

    // 1. read_key = tanh(h_prev @ read_W.T + read_b)          (8 MB)
    gemv64_kernel<<<256, 256, 0, stream>>>(read_W, h_prev, read_b, rk, MEM_DIM, 512, 1);
    // 2. sim = memory @ read_key                              (16 MB)
    gemv64_kernel<<<1024, 256, 0, stream>>>(memory, rk, nullptr, sim, MEM_SLOTS, 256, 0);
    // 3. read_weights = softmax(sim); usage_new = usage + rw
    softmax_rw_kernel<<<1, 1024, 0, stream>>>(sim, usage, rw, usage_new);
    // 4-5. read_vec = rw @ memory (two-stage deterministic)   (16 MB, L3)
    readvec_partial_kernel<<<64, 256, 0, stream>>>(memory, rw, partial);
    readvec_reduce_kernel<<<1, 1024, 0, stream>>>(partial, x, xcat, hvcat);
    // 6. gates = xcat @ W_ih.T + b_ih + h_prev @ W_hh.T + b_hh   (160 MB)
    gates_kernel<<<2048, 256, 0, stream>>>(W_ih, W_hh, b_ih, b_hh, xcat, h_prev, gates);
    // 7. LSTM elementwise -> c_new, h_new
    lstm_elem_kernel<<<8, 256, 0, stream>>>(gates, c_prev, c_new, h_new, hvcat);
    // 8. params = h_new @ head_W.T + head_b                   (58.7 MB)
    gemv64_kernel<<<1793, 256, 0, stream>>>(head_W, h_new, head_b, params, 7169, 512, 0);
    // 9. w = softmax(logits)*sigmoid(gate); erase/add precompute
    softmax_w_kernel<<<1, 1024, 0, stream>>>(params, wv, erase, addv);
    // 10. memory update                                        (32 MB r+w)
    memupdate_kernel<<<4096, 256, 0, stream>>>(memory, wv, erase, addv, usage_new, newmem);
    // 11. out = hvcat @ out_W.T + out_b                        (24 MB)
    gemv64_kernel<<<512, 256, 0, stream>>>(out_W, hvcat, out_b, out, OUTPUT_DIM, 768, 0);
}